// Round 2
// baseline (1948.649 us; speedup 1.0000x reference)
//
#include <hip/hip_runtime.h>
#include <cstddef>
#include <cstdint>

#define BHN 128
#define NSEQ 4096
#define EPSF 1e-6f

constexpr int K2_S = 8;
constexpr int K2_ROWS = NSEQ / K2_S;        // 512
constexpr int K2_TILES = 8;                 // 8 tiles of 64 rows

__device__ __forceinline__ float4 exp4(float4 x) {
    return make_float4(__expf(x.x), __expf(x.y), __expf(x.z), __expf(x.w));
}

// ---------------------------------------------------------------------------
// Kernel 2: per-(bh, n-split) partial ctx[d][e] = sum_n exp(k[n,d]) * v[n,e]
// plus partial colsum[d]. Software-pipelined: tile t+1 K/V prefetched into
// VGPRs during compute of tile t (reg loads are not drained by s_barrier).
// ---------------------------------------------------------------------------
__global__ __launch_bounds__(256, 4)
void k2_partial_ctx(const float* __restrict__ K, const float* __restrict__ V,
                    float* __restrict__ part_ctx, float* __restrict__ part_cs)
{
    __shared__ __align__(16) float ke[64 * 64];
    __shared__ __align__(16) float vs[64 * 64];
    __shared__ float csb[256];

    const int bh  = blockIdx.x;
    const int s   = blockIdx.y;
    const int tid = threadIdx.x;
    const int w    = tid >> 6;
    const int lane = tid & 63;
    const int l8   = lane & 7;
    const int h8   = lane >> 3;

    const float4* Kg = (const float4*)(K + ((size_t)bh * NSEQ + (size_t)s * K2_ROWS) * 64);
    const float4* Vg = (const float4*)(V + ((size_t)bh * NSEQ + (size_t)s * K2_ROWS) * 64);

    float acc[8][8];
    #pragma unroll
    for (int i = 0; i < 8; ++i)
        #pragma unroll
        for (int j = 0; j < 8; ++j) acc[i][j] = 0.f;
    float cs[8];
    #pragma unroll
    for (int i = 0; i < 8; ++i) cs[i] = 0.f;

    float4* ke4 = (float4*)ke;
    float4* vs4 = (float4*)vs;

    // preload tile 0 into regs
    float4 kreg[4], vreg[4];
    #pragma unroll
    for (int p = 0; p < 4; ++p) {
        kreg[p] = Kg[tid + p * 256];
        vreg[p] = Vg[tid + p * 256];
    }

    for (int t = 0; t < K2_TILES; ++t) {
        if (t) __syncthreads();             // readers of previous tile done
        #pragma unroll
        for (int p = 0; p < 4; ++p) {
            ke4[tid + p * 256] = exp4(kreg[p]);
            vs4[tid + p * 256] = vreg[p];
        }
        if (t + 1 < K2_TILES) {             // prefetch next tile (overlaps compute)
            #pragma unroll
            for (int p = 0; p < 4; ++p) {
                kreg[p] = Kg[(t + 1) * 1024 + tid + p * 256];
                vreg[p] = Vg[(t + 1) * 1024 + tid + p * 256];
            }
        }
        __syncthreads();
        #pragma unroll
        for (int nn = 0; nn < 16; ++nn) {
            const int n = w * 16 + nn;
            float4 a0 = ke4[n * 16 + h8];
            float4 a1 = ke4[n * 16 + 8 + h8];
            float4 b0 = vs4[n * 16 + l8];
            float4 b1 = vs4[n * 16 + 8 + l8];
            float a[8] = {a0.x, a0.y, a0.z, a0.w, a1.x, a1.y, a1.z, a1.w};
            float b[8] = {b0.x, b0.y, b0.z, b0.w, b1.x, b1.y, b1.z, b1.w};
            #pragma unroll
            for (int i = 0; i < 8; ++i) cs[i] += a[i];
            #pragma unroll
            for (int i = 0; i < 8; ++i)
                #pragma unroll
                for (int j = 0; j < 8; ++j)
                    acc[i][j] = fmaf(a[i], b[j], acc[i][j]);
        }
    }
    __syncthreads();   // done reading tiles; ke/vs reusable as reduce buffers

    int dd[8];
    #pragma unroll
    for (int i = 0; i < 8; ++i)
        dd[i] = (i < 4) ? (4 * h8 + i) : (32 + 4 * h8 + (i - 4));

    // ---- parallel tree reduction across waves
    if (l8 == 0) {
        #pragma unroll
        for (int i = 0; i < 8; ++i) csb[w * 64 + dd[i]] = cs[i];
    }
    if (w >= 2) {
        float* dst = (w == 2) ? ke : vs;
        #pragma unroll
        for (int i = 0; i < 8; ++i)
            #pragma unroll
            for (int ej = 0; ej < 2; ++ej)
                *(float4*)&dst[dd[i] * 64 + ej * 32 + 4 * l8] =
                    make_float4(acc[i][4*ej+0], acc[i][4*ej+1],
                                acc[i][4*ej+2], acc[i][4*ej+3]);
    }
    __syncthreads();
    if (w < 2) {
        const float* src = (w == 0) ? ke : vs;
        #pragma unroll
        for (int i = 0; i < 8; ++i)
            #pragma unroll
            for (int ej = 0; ej < 2; ++ej) {
                float4 o = *(const float4*)&src[dd[i] * 64 + ej * 32 + 4 * l8];
                acc[i][4*ej+0] += o.x; acc[i][4*ej+1] += o.y;
                acc[i][4*ej+2] += o.z; acc[i][4*ej+3] += o.w;
            }
    }
    __syncthreads();
    if (w == 1) {
        #pragma unroll
        for (int i = 0; i < 8; ++i)
            #pragma unroll
            for (int ej = 0; ej < 2; ++ej)
                *(float4*)&ke[dd[i] * 64 + ej * 32 + 4 * l8] =
                    make_float4(acc[i][4*ej+0], acc[i][4*ej+1],
                                acc[i][4*ej+2], acc[i][4*ej+3]);
    }
    __syncthreads();
    if (w == 0) {
        #pragma unroll
        for (int i = 0; i < 8; ++i) {
            #pragma unroll
            for (int ej = 0; ej < 2; ++ej) {
                float4 o = *(const float4*)&ke[dd[i] * 64 + ej * 32 + 4 * l8];
                *(float4*)&vs[dd[i] * 64 + ej * 32 + 4 * l8] =
                    make_float4(acc[i][4*ej+0] + o.x, acc[i][4*ej+1] + o.y,
                                acc[i][4*ej+2] + o.z, acc[i][4*ej+3] + o.w);
            }
            if (l8 == 0) {
                float c = csb[dd[i]] + csb[64 + dd[i]] + csb[128 + dd[i]] + csb[192 + dd[i]];
                csb[dd[i]] = c;
            }
        }
    }
    __syncthreads();

    // ---- coalesced store of partials
    float4* pc = (float4*)(part_ctx + (size_t)(bh * K2_S + s) * 4096);
    #pragma unroll
    for (int p = 0; p < 4; ++p)
        pc[tid + p * 256] = vs4[tid + p * 256];
    if (tid < 16)
        ((float4*)(part_cs + (size_t)(bh * K2_S + s) * 64))[tid] = ((const float4*)csb)[tid];
}

// ---------------------------------------------------------------------------
// Kernel 2b: reduce the 8 partials, finalize ctxf = raw / (colsum*(1+eps))
// ---------------------------------------------------------------------------
__global__ __launch_bounds__(256)
void k2_reduce(const float* __restrict__ part_ctx, const float* __restrict__ part_cs,
               float* __restrict__ ctxf)
{
    __shared__ float inv_cs[64];
    const int bh  = blockIdx.x;
    const int tid = threadIdx.x;
    if (tid < 64) {
        float c = 0.f;
        #pragma unroll
        for (int s = 0; s < K2_S; ++s)
            c += part_cs[(size_t)(bh * K2_S + s) * 64 + tid];
        inv_cs[tid] = 1.0f / (c * (1.0f + EPSF));
    }
    __syncthreads();
    const float4* pc = (const float4*)(part_ctx + (size_t)bh * K2_S * 4096);
    float4* cf = (float4*)(ctxf + (size_t)bh * 4096);
    const int f = blockIdx.y * 256 + tid;
    float4 sum = make_float4(0.f, 0.f, 0.f, 0.f);
    #pragma unroll
    for (int s = 0; s < K2_S; ++s) {
        float4 x = pc[s * 1024 + f];
        sum.x += x.x; sum.y += x.y; sum.z += x.z; sum.w += x.w;
    }
    const float inv = inv_cs[f >> 4];
    sum.x *= inv; sum.y *= inv; sum.z *= inv; sum.w *= inv;
    cf[f] = sum;
}

// ---------------------------------------------------------------------------
// Kernel 3: out[n][e] = (sum_d exp(q[n,d]) * ctxf[d][e]) / rowsum[n]
// 256 threads / 256 rows per block; q staged in two 32-col halves so LDS
// stays at ~51 KB -> 3 blocks/CU (12 waves). Half-1 prefetched into regs.
// ---------------------------------------------------------------------------
constexpr int K3R = 256;
constexpr int QST = 34;   // 32 + 2 pad (even => aligned float2, 2-way banks = free)

__global__ __launch_bounds__(256, 3)
void k3_out(const float* __restrict__ Q, const float* __restrict__ ctxf,
            float* __restrict__ out)
{
    __shared__ __align__(16) float qe[K3R * QST];   // 34.8 KB
    __shared__ __align__(16) float ctx_s[4096];     // 16.4 KB
    __shared__ float rs[K3R];                       // 1 KB

    const int bh  = blockIdx.x;
    const int n0  = blockIdx.y * K3R;
    const int tid = threadIdx.x;
    const int w    = tid >> 6;
    const int lane = tid & 63;
    const int l8   = lane & 7;
    const int h8   = lane >> 3;
    const int rq   = tid >> 3;   // staging row-group 0..31
    const int c8   = tid & 7;    // staging col-chunk 0..7

    const float4* Qg = (const float4*)(Q + ((size_t)bh * NSEQ + n0) * 64);
    const float4* Cg = (const float4*)(ctxf + (size_t)bh * 4096);

    // preamble loads: ctx + q half 0
    float4 creg[4];
    #pragma unroll
    for (int p = 0; p < 4; ++p) creg[p] = Cg[tid + p * 256];
    float4 qreg[8];
    #pragma unroll
    for (int p = 0; p < 8; ++p) qreg[p] = Qg[(rq + 32 * p) * 16 + c8];

    float4* cs4 = (float4*)ctx_s;
    #pragma unroll
    for (int p = 0; p < 4; ++p) cs4[tid + p * 256] = creg[p];

    #pragma unroll
    for (int p = 0; p < 8; ++p) {
        const int r = rq + 32 * p;
        float4 e = exp4(qreg[p]);
        float ssum = e.x + e.y + e.z + e.w;
        ssum += __shfl_xor(ssum, 1);
        ssum += __shfl_xor(ssum, 2);
        ssum += __shfl_xor(ssum, 4);
        if (c8 == 0) rs[r] = ssum;
        *(float4*)&qe[r * QST + 4 * c8] = e;
    }
    // prefetch q half 1 (overlaps half-0 compute)
    #pragma unroll
    for (int p = 0; p < 8; ++p) qreg[p] = Qg[(rq + 32 * p) * 16 + 8 + c8];
    __syncthreads();

    int rowi[8];
    #pragma unroll
    for (int i = 0; i < 8; ++i)
        rowi[i] = 64 * w + ((i < 4) ? (4 * h8 + i) : (32 + 4 * h8 + (i - 4)));

    float acc[8][8];
    #pragma unroll
    for (int i = 0; i < 8; ++i)
        #pragma unroll
        for (int j = 0; j < 8; ++j) acc[i][j] = 0.f;

    // ---- half 0: d = 0..31
    #pragma unroll
    for (int dc = 0; dc < 32; dc += 2) {
        float2 aq[8];
        #pragma unroll
        for (int i = 0; i < 8; ++i)
            aq[i] = *(const float2*)(qe + rowi[i] * QST + dc);
        float4 b00 = *(const float4*)(ctx_s + dc * 64 + 4 * l8);
        float4 b01 = *(const float4*)(ctx_s + dc * 64 + 32 + 4 * l8);
        float4 b10 = *(const float4*)(ctx_s + (dc + 1) * 64 + 4 * l8);
        float4 b11 = *(const float4*)(ctx_s + (dc + 1) * 64 + 32 + 4 * l8);
        float b0[8] = {b00.x,b00.y,b00.z,b00.w,b01.x,b01.y,b01.z,b01.w};
        float b1[8] = {b10.x,b10.y,b10.z,b10.w,b11.x,b11.y,b11.z,b11.w};
        #pragma unroll
        for (int i = 0; i < 8; ++i)
            #pragma unroll
            for (int j = 0; j < 8; ++j) {
                acc[i][j] = fmaf(aq[i].x, b0[j], acc[i][j]);
                acc[i][j] = fmaf(aq[i].y, b1[j], acc[i][j]);
            }
    }
    __syncthreads();

    // ---- stage half 1
    #pragma unroll
    for (int p = 0; p < 8; ++p) {
        const int r = rq + 32 * p;
        float4 e = exp4(qreg[p]);
        float ssum = e.x + e.y + e.z + e.w;
        ssum += __shfl_xor(ssum, 1);
        ssum += __shfl_xor(ssum, 2);
        ssum += __shfl_xor(ssum, 4);
        if (c8 == 0) rs[r] += ssum;
        *(float4*)&qe[r * QST + 4 * c8] = e;
    }
    __syncthreads();

    // ---- half 1: d = 32..63
    #pragma unroll
    for (int dc = 0; dc < 32; dc += 2) {
        float2 aq[8];
        #pragma unroll
        for (int i = 0; i < 8; ++i)
            aq[i] = *(const float2*)(qe + rowi[i] * QST + dc);
        float4 b00 = *(const float4*)(ctx_s + (32 + dc) * 64 + 4 * l8);
        float4 b01 = *(const float4*)(ctx_s + (32 + dc) * 64 + 32 + 4 * l8);
        float4 b10 = *(const float4*)(ctx_s + (33 + dc) * 64 + 4 * l8);
        float4 b11 = *(const float4*)(ctx_s + (33 + dc) * 64 + 32 + 4 * l8);
        float b0[8] = {b00.x,b00.y,b00.z,b00.w,b01.x,b01.y,b01.z,b01.w};
        float b1[8] = {b10.x,b10.y,b10.z,b10.w,b11.x,b11.y,b11.z,b11.w};
        #pragma unroll
        for (int i = 0; i < 8; ++i)
            #pragma unroll
            for (int j = 0; j < 8; ++j) {
                acc[i][j] = fmaf(aq[i].x, b0[j], acc[i][j]);
                acc[i][j] = fmaf(aq[i].y, b1[j], acc[i][j]);
            }
    }

    // ---- epilogue
    float4* og = (float4*)(out + ((size_t)bh * NSEQ + n0) * 64);
    #pragma unroll
    for (int i = 0; i < 8; ++i) {
        const float inv = 1.0f / rs[rowi[i]];
        #pragma unroll
        for (int ej = 0; ej < 2; ++ej)
            og[rowi[i] * 16 + ej * 8 + l8] =
                make_float4(acc[i][4*ej+0]*inv, acc[i][4*ej+1]*inv,
                            acc[i][4*ej+2]*inv, acc[i][4*ej+3]*inv);
    }
}

// ---------------------------------------------------------------------------
extern "C" void kernel_launch(void* const* d_in, const int* in_sizes, int n_in,
                              void* d_out, int out_size, void* d_ws, size_t ws_size,
                              hipStream_t stream)
{
    const float* q = (const float*)d_in[0];
    const float* k = (const float*)d_in[1];
    const float* v = (const float*)d_in[2];
    float* out = (float*)d_out;

    // d_out doubles as scratch for the 16.8 MB ctx partials: k2_reduce fully
    // consumes them before k3 overwrites d_out (stream-ordered dispatches).
    float* part_ctx = (float*)d_out;                 // 1024 * 4096 floats
    float* part_cs  = (float*)d_ws;                  // 1024 * 64 floats
    float* ctxf     = part_cs + (size_t)1024 * 64;   // 128 * 4096 floats

    k2_partial_ctx<<<dim3(BHN, K2_S), 256, 0, stream>>>(k, v, part_ctx, part_cs);
    k2_reduce<<<dim3(BHN, 4), 256, 0, stream>>>(part_ctx, part_cs, ctxf);
    k3_out<<<dim3(BHN, NSEQ / K3R), 256, 0, stream>>>(q, ctxf, out);
}